// Round 1
// baseline (1041.186 us; speedup 1.0000x reference)
//
#include <hip/hip_runtime.h>
#include <cstdint>
#include <cstddef>

// ---------- types ----------
typedef __attribute__((ext_vector_type(8))) short short8;   // 8 bf16 (4 VGPRs) MFMA A/B frag
typedef __attribute__((ext_vector_type(4))) float f32x4;    // MFMA C/D frag

#define MFMA_BF16(a, b, c) __builtin_amdgcn_mfma_f32_16x16x32_bf16((a), (b), (c), 0, 0, 0)

union F2U { float f; unsigned int u; };
union U4S8 { uint4 u4; unsigned short s[8]; short8 v; };

__device__ __forceinline__ unsigned short f2bf(float f) {
  F2U x; x.f = f;
  unsigned int r = x.u + 0x7fffu + ((x.u >> 16) & 1u);  // RNE
  return (unsigned short)(r >> 16);
}
__device__ __forceinline__ float bf2f(unsigned short s) {
  F2U x; x.u = ((unsigned int)s) << 16;
  return x.f;
}

// ---------- problem constants ----------
#define HIDDEN 2048
#define NHEADS 32
#define NKV 8
#define HDIM 64
#define SEQ 2048
#define BATCH 2
#define NTOK (BATCH * SEQ)   // 4096

// =====================================================================
// RoPE table: cos/sin [SEQ][32] fp32
// =====================================================================
__global__ __launch_bounds__(256) void rope_table_kernel(float* __restrict__ ct, float* __restrict__ st) {
  int idx = blockIdx.x * 256 + threadIdx.x;     // 0 .. 65535
  int s = idx >> 5;
  int i = idx & 31;
  // inv_freq = theta^(-i/32), theta = 10000 ; ln(10000) = 9.210340371976184
  float invf = expf(-(float)i * (9.210340371976184f / 32.0f));
  float f = (float)s * invf;
  ct[idx] = cosf(f);
  st[idx] = sinf(f);
}

// =====================================================================
// GEMM: C[M,N] = A[M,K] @ B[K,N]; A fp32 or bf16, B fp32 (weights),
// C fp32 or bf16. 64x64 tile, BK=32, 256 threads (4 waves, 2x2 of 32x32).
// =====================================================================
template<bool A_BF16, bool OUT_BF16>
__global__ __launch_bounds__(256) void gemm_kernel(const void* __restrict__ Ap,
                                                   const float* __restrict__ Bw,
                                                   void* __restrict__ Cp,
                                                   int M, int N, int K) {
  __shared__ __align__(16) unsigned short lds_a[64][40];   // [m][k], pad 40
  __shared__ __align__(16) unsigned short lds_bt[64][40];  // [n][k], pad 40

  const int t = threadIdx.x;
  const int lane = t & 63;
  const int w = t >> 6;
  const int lr = lane & 15, lh = lane >> 4;
  const int m0 = blockIdx.y * 64, n0 = blockIdx.x * 64;
  const int wr = (w >> 1) * 32, wc = (w & 1) * 32;

  const int arow = t >> 2, acg = (t & 3) * 8;   // A stage: [64 rows][4x8 cols]
  const int bkr = t >> 3, bcg = (t & 7) * 8;    // B stage: [32 k][8x8 n]

  f32x4 acc[2][2] = {};

  for (int k0 = 0; k0 < K; k0 += 32) {
    __syncthreads();
    // ---- stage A tile [64][32] -> lds_a (bf16) ----
    {
      U4S8 pack;
      if constexpr (A_BF16) {
        const unsigned short* As = (const unsigned short*)Ap + (size_t)(m0 + arow) * K + k0 + acg;
        pack.u4 = *(const uint4*)As;
      } else {
        const float* As = (const float*)Ap + (size_t)(m0 + arow) * K + k0 + acg;
        float4 a0 = *(const float4*)As;
        float4 a1 = *(const float4*)(As + 4);
        pack.s[0] = f2bf(a0.x); pack.s[1] = f2bf(a0.y); pack.s[2] = f2bf(a0.z); pack.s[3] = f2bf(a0.w);
        pack.s[4] = f2bf(a1.x); pack.s[5] = f2bf(a1.y); pack.s[6] = f2bf(a1.z); pack.s[7] = f2bf(a1.w);
      }
      *(short8*)&lds_a[arow][acg] = pack.v;
    }
    // ---- stage B tile [32][64] transposed -> lds_bt[n][k] (bf16) ----
    {
      const float* Bs = Bw + (size_t)(k0 + bkr) * N + n0 + bcg;
      float4 b0 = *(const float4*)Bs;
      float4 b1 = *(const float4*)(Bs + 4);
      lds_bt[bcg + 0][bkr] = f2bf(b0.x);
      lds_bt[bcg + 1][bkr] = f2bf(b0.y);
      lds_bt[bcg + 2][bkr] = f2bf(b0.z);
      lds_bt[bcg + 3][bkr] = f2bf(b0.w);
      lds_bt[bcg + 4][bkr] = f2bf(b1.x);
      lds_bt[bcg + 5][bkr] = f2bf(b1.y);
      lds_bt[bcg + 6][bkr] = f2bf(b1.z);
      lds_bt[bcg + 7][bkr] = f2bf(b1.w);
    }
    __syncthreads();
    // ---- compute ----
    short8 af[2], bfr[2];
    af[0]  = *(const short8*)&lds_a[wr + lr][lh * 8];
    af[1]  = *(const short8*)&lds_a[wr + 16 + lr][lh * 8];
    bfr[0] = *(const short8*)&lds_bt[wc + lr][lh * 8];
    bfr[1] = *(const short8*)&lds_bt[wc + 16 + lr][lh * 8];
    acc[0][0] = MFMA_BF16(af[0], bfr[0], acc[0][0]);
    acc[0][1] = MFMA_BF16(af[0], bfr[1], acc[0][1]);
    acc[1][0] = MFMA_BF16(af[1], bfr[0], acc[1][0]);
    acc[1][1] = MFMA_BF16(af[1], bfr[1], acc[1][1]);
  }

  // ---- epilogue: D layout col = lane&15, row = (lane>>4)*4 + reg ----
  #pragma unroll
  for (int i = 0; i < 2; ++i) {
    #pragma unroll
    for (int j = 0; j < 2; ++j) {
      #pragma unroll
      for (int r = 0; r < 4; ++r) {
        int row = m0 + wr + i * 16 + lh * 4 + r;
        int col = n0 + wc + j * 16 + lr;
        if constexpr (OUT_BF16) {
          ((unsigned short*)Cp)[(size_t)row * N + col] = f2bf(acc[i][j][r]);
        } else {
          ((float*)Cp)[(size_t)row * N + col] = acc[i][j][r];
        }
      }
    }
  }
}

// =====================================================================
// RoPE apply: Qb0 [4096][2048] bf16, Kb0 [4096][512] bf16 ->
//   Qb [B][32][S][64], Kb [B][8][S][64] (bf16)
// One 64-lane unit per (token, head-slot); head-slot 0..31 = Q, 32..39 = K.
// =====================================================================
__global__ __launch_bounds__(256) void rope_apply_kernel(const unsigned short* __restrict__ Qb0,
                                                         const unsigned short* __restrict__ Kb0,
                                                         const float* __restrict__ ct,
                                                         const float* __restrict__ st,
                                                         unsigned short* __restrict__ Qb,
                                                         unsigned short* __restrict__ Kb) {
  int uid = blockIdx.x * 4 + (threadIdx.x >> 6);
  int d = threadIdx.x & 63;
  int m = uid / 40;
  int hh = uid - m * 40;
  int b = m >> 11, s = m & 2047;

  const unsigned short* src;
  unsigned short* dst;
  if (hh < 32) {
    src = Qb0 + (size_t)m * (NHEADS * HDIM) + hh * HDIM;
    dst = Qb + (((size_t)(b * NHEADS + hh)) * SEQ + s) * HDIM;
  } else {
    int h2 = hh - 32;
    src = Kb0 + (size_t)m * (NKV * HDIM) + h2 * HDIM;
    dst = Kb + (((size_t)(b * NKV + h2)) * SEQ + s) * HDIM;
  }
  float v = bf2f(src[d]);
  float p = __shfl_xor(v, 32, 64);       // partner element d^32
  int fi = d & 31;
  float c = ct[s * 32 + fi];
  float sn = st[s * 32 + fi];
  float sgn = (d < 32) ? -1.0f : 1.0f;   // rotate_half: [-x2, x1]
  float o = v * c + sgn * p * sn;
  dst[d] = f2bf(o);
}

// =====================================================================
// V pack/transpose: Vb0 [4096][512] bf16 -> Vt [B][KV][64][S] bf16
// =====================================================================
__global__ __launch_bounds__(256) void v_pack_kernel(const unsigned short* __restrict__ Vb0,
                                                     unsigned short* __restrict__ Vt) {
  int idx = blockIdx.x * 256 + threadIdx.x;  // 0 .. 2M-1
  int m = idx >> 9;
  int c = idx & 511;
  int b = m >> 11, s = m & 2047;
  int kv = c >> 6, d = c & 63;
  Vt[(((size_t)(b * NKV + kv)) * HDIM + d) * SEQ + s] = Vb0[idx];
}

// =====================================================================
// Flash attention (causal, GQA). Block: (q_tile 64, head, batch), 4 waves.
// Wave w: 16 query rows. KV tiles of 64 keys. Online softmax in fp32.
// =====================================================================
__global__ __launch_bounds__(256) void flash_kernel(const unsigned short* __restrict__ Qb,
                                                    const unsigned short* __restrict__ Kb,
                                                    const unsigned short* __restrict__ Vt,
                                                    unsigned short* __restrict__ Ob) {
  const int st = blockIdx.x;   // q tile 0..31
  const int h = blockIdx.y;    // q head 0..31
  const int b = blockIdx.z;
  const int kv = h >> 2;
  const int t = threadIdx.x, lane = t & 63, w = t >> 6;
  const int lr = lane & 15, lh = lane >> 4;

  __shared__ __align__(16) unsigned short lds_p[4][16][72];  // per-wave P tile, padded

  const unsigned short* Qh = Qb + ((size_t)(b * NHEADS + h)) * SEQ * HDIM;
  const unsigned short* Kh = Kb + ((size_t)(b * NKV + kv)) * SEQ * HDIM;
  const unsigned short* Vh = Vt + ((size_t)(b * NKV + kv)) * HDIM * SEQ;

  const int q0 = st * 64 + w * 16;

  short8 qf0 = *(const short8*)&Qh[(q0 + lr) * HDIM + lh * 8];
  short8 qf1 = *(const short8*)&Qh[(q0 + lr) * HDIM + 32 + lh * 8];

  f32x4 o_acc[4] = {};
  float m_run[4] = {-1e30f, -1e30f, -1e30f, -1e30f};
  float l_run[4] = {0.f, 0.f, 0.f, 0.f};

  for (int tt = 0; tt <= st; ++tt) {
    const int kt0 = tt * 64;
    // ---- scores S = Q K^T ----
    f32x4 sa[4] = {};
    #pragma unroll
    for (int j = 0; j < 4; ++j) {
      const unsigned short* kp = &Kh[(kt0 + j * 16 + lr) * HDIM + lh * 8];
      short8 kf0 = *(const short8*)kp;
      short8 kf1 = *(const short8*)(kp + 32);
      sa[j] = MFMA_BF16(qf0, kf0, sa[j]);
      sa[j] = MFMA_BF16(qf1, kf1, sa[j]);
    }
    // ---- scale + causal mask + row max ----
    float rmax[4] = {-1e30f, -1e30f, -1e30f, -1e30f};
    #pragma unroll
    for (int j = 0; j < 4; ++j) {
      const int key = kt0 + j * 16 + lr;
      #pragma unroll
      for (int r = 0; r < 4; ++r) {
        float sc = sa[j][r] * 0.125f;
        if (key > q0 + lh * 4 + r) sc = -1e30f;
        sa[j][r] = sc;
        rmax[r] = fmaxf(rmax[r], sc);
      }
    }
    #pragma unroll
    for (int msk = 1; msk < 16; msk <<= 1) {
      #pragma unroll
      for (int r = 0; r < 4; ++r)
        rmax[r] = fmaxf(rmax[r], __shfl_xor(rmax[r], msk, 64));
    }
    // ---- online softmax update ----
    float alpha[4], psum[4] = {0.f, 0.f, 0.f, 0.f};
    #pragma unroll
    for (int r = 0; r < 4; ++r) {
      float mn = fmaxf(m_run[r], rmax[r]);
      alpha[r] = __expf(m_run[r] - mn);
      m_run[r] = mn;
    }
    #pragma unroll
    for (int j = 0; j < 4; ++j) {
      #pragma unroll
      for (int r = 0; r < 4; ++r) {
        float p = __expf(sa[j][r] - m_run[r]);
        sa[j][r] = p;
        psum[r] += p;
      }
    }
    #pragma unroll
    for (int msk = 1; msk < 16; msk <<= 1) {
      #pragma unroll
      for (int r = 0; r < 4; ++r)
        psum[r] += __shfl_xor(psum[r], msk, 64);
    }
    #pragma unroll
    for (int r = 0; r < 4; ++r)
      l_run[r] = l_run[r] * alpha[r] + psum[r];
    #pragma unroll
    for (int dj = 0; dj < 4; ++dj) {
      #pragma unroll
      for (int r = 0; r < 4; ++r)
        o_acc[dj][r] *= alpha[r];
    }
    // ---- P (D-layout) -> LDS -> A-layout frags ----
    #pragma unroll
    for (int j = 0; j < 4; ++j) {
      #pragma unroll
      for (int r = 0; r < 4; ++r)
        lds_p[w][lh * 4 + r][j * 16 + lr] = f2bf(sa[j][r]);
    }
    __syncthreads();
    short8 pf0 = *(const short8*)&lds_p[w][lr][lh * 8];
    short8 pf1 = *(const short8*)&lds_p[w][lr][32 + lh * 8];
    // ---- O += P V ----
    #pragma unroll
    for (int dj = 0; dj < 4; ++dj) {
      const unsigned short* vp = &Vh[(dj * 16 + lr) * SEQ + kt0 + lh * 8];
      short8 vf0 = *(const short8*)vp;
      short8 vf1 = *(const short8*)(vp + 32);
      o_acc[dj] = MFMA_BF16(pf0, vf0, o_acc[dj]);
      o_acc[dj] = MFMA_BF16(pf1, vf1, o_acc[dj]);
    }
    __syncthreads();
  }

  // ---- write O (bf16) as [token][h*64+d] ----
  #pragma unroll
  for (int r = 0; r < 4; ++r) {
    float inv = 1.0f / l_run[r];
    size_t rowbase = (size_t)(b * SEQ + q0 + lh * 4 + r) * (NHEADS * HDIM) + h * HDIM;
    #pragma unroll
    for (int dj = 0; dj < 4; ++dj)
      Ob[rowbase + dj * 16 + lr] = f2bf(o_acc[dj][r] * inv);
  }
}

// =====================================================================
// launcher
// =====================================================================
extern "C" void kernel_launch(void* const* d_in, const int* in_sizes, int n_in,
                              void* d_out, int out_size, void* d_ws, size_t ws_size,
                              hipStream_t stream) {
  const float* X  = (const float*)d_in[0];
  const float* Wq = (const float*)d_in[1];
  const float* Wk = (const float*)d_in[2];
  const float* Wv = (const float*)d_in[3];
  const float* Wo = (const float*)d_in[4];
  float* out = (float*)d_out;

  char* ws = (char*)d_ws;
  size_t off = 0;
  auto carve = [&](size_t bytes) -> void* {
    void* p = ws + off;
    off += (bytes + 255) & ~(size_t)255;
    return p;
  };
  float* rope_cos = (float*)carve((size_t)SEQ * 32 * 4);
  float* rope_sin = (float*)carve((size_t)SEQ * 32 * 4);
  unsigned short* Qb0 = (unsigned short*)carve((size_t)NTOK * NHEADS * HDIM * 2);
  unsigned short* Kb0 = (unsigned short*)carve((size_t)NTOK * NKV * HDIM * 2);
  unsigned short* Vb0 = (unsigned short*)carve((size_t)NTOK * NKV * HDIM * 2);
  unsigned short* Qb  = (unsigned short*)carve((size_t)NTOK * NHEADS * HDIM * 2);
  unsigned short* Kb  = (unsigned short*)carve((size_t)NTOK * NKV * HDIM * 2);
  unsigned short* Vt  = (unsigned short*)carve((size_t)NTOK * NKV * HDIM * 2);
  unsigned short* Ob  = (unsigned short*)carve((size_t)NTOK * NHEADS * HDIM * 2);

  // 1. RoPE tables
  rope_table_kernel<<<dim3(256), dim3(256), 0, stream>>>(rope_cos, rope_sin);

  // 2. QKV projections (bf16 outputs)
  gemm_kernel<false, true><<<dim3((NHEADS * HDIM) / 64, NTOK / 64), dim3(256), 0, stream>>>(
      X, Wq, Qb0, NTOK, NHEADS * HDIM, HIDDEN);
  gemm_kernel<false, true><<<dim3((NKV * HDIM) / 64, NTOK / 64), dim3(256), 0, stream>>>(
      X, Wk, Kb0, NTOK, NKV * HDIM, HIDDEN);
  gemm_kernel<false, true><<<dim3((NKV * HDIM) / 64, NTOK / 64), dim3(256), 0, stream>>>(
      X, Wv, Vb0, NTOK, NKV * HDIM, HIDDEN);

  // 3. RoPE apply (Q and K), layout to [b][h][s][d]
  rope_apply_kernel<<<dim3((NTOK * 40) / 4), dim3(256), 0, stream>>>(
      Qb0, Kb0, rope_cos, rope_sin, Qb, Kb);

  // 4. V transpose to [b][kv][d][s]
  v_pack_kernel<<<dim3((NTOK * NKV * HDIM) / 256), dim3(256), 0, stream>>>(Vb0, Vt);

  // 5. Flash attention
  flash_kernel<<<dim3(SEQ / 64, NHEADS, BATCH), dim3(256), 0, stream>>>(Qb, Kb, Vt, Ob);

  // 6. Output projection (fp32 out)
  gemm_kernel<true, false><<<dim3(HIDDEN / 64, NTOK / 64), dim3(256), 0, stream>>>(
      Ob, Wo, out, NTOK, HIDDEN, HIDDEN);
}

// Round 2
// 763.802 us; speedup vs baseline: 1.3632x; 1.3632x over previous
//
#include <hip/hip_runtime.h>
#include <cstdint>
#include <cstddef>

// ---------- types ----------
typedef __attribute__((ext_vector_type(8))) short short8;   // 8 bf16 MFMA A/B frag
typedef __attribute__((ext_vector_type(4))) float f32x4;    // 16x16 C/D frag
typedef __attribute__((ext_vector_type(16))) float f32x16;  // 32x32 C/D frag

#define MFMA16(a, b, c) __builtin_amdgcn_mfma_f32_16x16x32_bf16((a), (b), (c), 0, 0, 0)
#define MFMA32(a, b, c) __builtin_amdgcn_mfma_f32_32x32x16_bf16((a), (b), (c), 0, 0, 0)

union F2U { float f; unsigned int u; };
union U4S8 { uint4 u4; unsigned short s[8]; short8 v; };

__device__ __forceinline__ unsigned short f2bf(float f) {
  F2U x; x.f = f;
  unsigned int r = x.u + 0x7fffu + ((x.u >> 16) & 1u);  // RNE
  return (unsigned short)(r >> 16);
}
__device__ __forceinline__ float bf2f(unsigned short s) {
  F2U x; x.u = ((unsigned int)s) << 16;
  return x.f;
}

// ---------- problem constants ----------
#define HIDDEN 2048
#define NHEADS 32
#define NKV 8
#define HDIM 64
#define SEQ 2048
#define BATCH 2
#define NTOK (BATCH * SEQ)   // 4096

// =====================================================================
// RoPE table: cos/sin [SEQ][32] fp32
// =====================================================================
__global__ __launch_bounds__(256) void rope_table_kernel(float* __restrict__ ct, float* __restrict__ st) {
  int idx = blockIdx.x * 256 + threadIdx.x;     // 0 .. 65535
  int s = idx >> 5;
  int i = idx & 31;
  float invf = expf(-(float)i * (9.210340371976184f / 32.0f));  // 10000^(-i/32)
  float f = (float)s * invf;
  ct[idx] = cosf(f);
  st[idx] = sinf(f);
}

// =====================================================================
// GEMM: C[M,N] = A[M,K] @ B[K,N]; 64x64 tile, BK=32, 4 waves.
// =====================================================================
template<bool A_BF16, bool OUT_BF16>
__global__ __launch_bounds__(256) void gemm_kernel(const void* __restrict__ Ap,
                                                   const float* __restrict__ Bw,
                                                   void* __restrict__ Cp,
                                                   int M, int N, int K) {
  __shared__ __align__(16) unsigned short lds_a[64][40];   // [m][k], pad 40
  __shared__ __align__(16) unsigned short lds_bt[64][40];  // [n][k], pad 40

  const int t = threadIdx.x;
  const int lane = t & 63;
  const int w = t >> 6;
  const int lr = lane & 15, lh = lane >> 4;
  const int m0 = blockIdx.y * 64, n0 = blockIdx.x * 64;
  const int wr = (w >> 1) * 32, wc = (w & 1) * 32;

  const int arow = t >> 2, acg = (t & 3) * 8;   // A stage: [64 rows][4x8 cols]
  const int bkr = t >> 3, bcg = (t & 7) * 8;    // B stage: [32 k][8x8 n]

  f32x4 acc[2][2] = {};

  for (int k0 = 0; k0 < K; k0 += 32) {
    __syncthreads();
    {
      U4S8 pack;
      if constexpr (A_BF16) {
        const unsigned short* As = (const unsigned short*)Ap + (size_t)(m0 + arow) * K + k0 + acg;
        pack.u4 = *(const uint4*)As;
      } else {
        const float* As = (const float*)Ap + (size_t)(m0 + arow) * K + k0 + acg;
        float4 a0 = *(const float4*)As;
        float4 a1 = *(const float4*)(As + 4);
        pack.s[0] = f2bf(a0.x); pack.s[1] = f2bf(a0.y); pack.s[2] = f2bf(a0.z); pack.s[3] = f2bf(a0.w);
        pack.s[4] = f2bf(a1.x); pack.s[5] = f2bf(a1.y); pack.s[6] = f2bf(a1.z); pack.s[7] = f2bf(a1.w);
      }
      *(short8*)&lds_a[arow][acg] = pack.v;
    }
    {
      const float* Bs = Bw + (size_t)(k0 + bkr) * N + n0 + bcg;
      float4 b0 = *(const float4*)Bs;
      float4 b1 = *(const float4*)(Bs + 4);
      lds_bt[bcg + 0][bkr] = f2bf(b0.x);
      lds_bt[bcg + 1][bkr] = f2bf(b0.y);
      lds_bt[bcg + 2][bkr] = f2bf(b0.z);
      lds_bt[bcg + 3][bkr] = f2bf(b0.w);
      lds_bt[bcg + 4][bkr] = f2bf(b1.x);
      lds_bt[bcg + 5][bkr] = f2bf(b1.y);
      lds_bt[bcg + 6][bkr] = f2bf(b1.z);
      lds_bt[bcg + 7][bkr] = f2bf(b1.w);
    }
    __syncthreads();
    short8 af[2], bfr[2];
    af[0]  = *(const short8*)&lds_a[wr + lr][lh * 8];
    af[1]  = *(const short8*)&lds_a[wr + 16 + lr][lh * 8];
    bfr[0] = *(const short8*)&lds_bt[wc + lr][lh * 8];
    bfr[1] = *(const short8*)&lds_bt[wc + 16 + lr][lh * 8];
    acc[0][0] = MFMA16(af[0], bfr[0], acc[0][0]);
    acc[0][1] = MFMA16(af[0], bfr[1], acc[0][1]);
    acc[1][0] = MFMA16(af[1], bfr[0], acc[1][0]);
    acc[1][1] = MFMA16(af[1], bfr[1], acc[1][1]);
  }

  #pragma unroll
  for (int i = 0; i < 2; ++i) {
    #pragma unroll
    for (int j = 0; j < 2; ++j) {
      #pragma unroll
      for (int r = 0; r < 4; ++r) {
        int row = m0 + wr + i * 16 + lh * 4 + r;
        int col = n0 + wc + j * 16 + lr;
        if constexpr (OUT_BF16) {
          ((unsigned short*)Cp)[(size_t)row * N + col] = f2bf(acc[i][j][r]);
        } else {
          ((float*)Cp)[(size_t)row * N + col] = acc[i][j][r];
        }
      }
    }
  }
}

// =====================================================================
// RoPE apply. Q additionally pre-scaled by 1/sqrt(HDIM) = 0.125 so the
// attention kernel needs no per-score scaling.
// =====================================================================
__global__ __launch_bounds__(256) void rope_apply_kernel(const unsigned short* __restrict__ Qb0,
                                                         const unsigned short* __restrict__ Kb0,
                                                         const float* __restrict__ ct,
                                                         const float* __restrict__ st,
                                                         unsigned short* __restrict__ Qb,
                                                         unsigned short* __restrict__ Kb) {
  int uid = blockIdx.x * 4 + (threadIdx.x >> 6);
  int d = threadIdx.x & 63;
  int m = uid / 40;
  int hh = uid - m * 40;
  int b = m >> 11, s = m & 2047;

  const unsigned short* src;
  unsigned short* dst;
  bool isq = (hh < 32);
  if (isq) {
    src = Qb0 + (size_t)m * (NHEADS * HDIM) + hh * HDIM;
    dst = Qb + (((size_t)(b * NHEADS + hh)) * SEQ + s) * HDIM;
  } else {
    int h2 = hh - 32;
    src = Kb0 + (size_t)m * (NKV * HDIM) + h2 * HDIM;
    dst = Kb + (((size_t)(b * NKV + h2)) * SEQ + s) * HDIM;
  }
  float v = bf2f(src[d]);
  float p = __shfl_xor(v, 32, 64);       // partner element d^32
  int fi = d & 31;
  float c = ct[s * 32 + fi];
  float sn = st[s * 32 + fi];
  float sgn = (d < 32) ? -1.0f : 1.0f;   // rotate_half: [-x2, x1]
  float o = v * c + sgn * p * sn;
  if (isq) o *= 0.125f;
  dst[d] = f2bf(o);
}

// =====================================================================
// V pack/transpose: Vb0 [4096][512] bf16 -> Vt [B][KV][64][S] bf16
// =====================================================================
__global__ __launch_bounds__(256) void v_pack_kernel(const unsigned short* __restrict__ Vb0,
                                                     unsigned short* __restrict__ Vt) {
  int idx = blockIdx.x * 256 + threadIdx.x;  // 0 .. 2M-1
  int m = idx >> 9;
  int c = idx & 511;
  int b = m >> 11, s = m & 2047;
  int kv = c >> 6, d = c & 63;
  Vt[(((size_t)(b * NKV + kv)) * HDIM + d) * SEQ + s] = Vb0[idx];
}

// =====================================================================
// Flash attention, 8-wave 32x32 swapped-QK^T structure (guide §B / m214).
// Block: 512 threads = 8 waves; wave w owns 32 q-rows. KV tiles of 32.
// S^T = mfma32(K, Q): lane holds 16 of 32 key-scores for query lane&31
// (partner lane^32 holds the rest). Softmax fully in-register.
// PV computed as O^T = mfma32(V^T, P^T); V^T frags read from Vt[d][s].
// No barriers in the main loop; waves independent.
// =====================================================================
__global__ __launch_bounds__(512) void flash_kernel(const unsigned short* __restrict__ Qb,
                                                    const unsigned short* __restrict__ Kb,
                                                    const unsigned short* __restrict__ Vt,
                                                    unsigned short* __restrict__ Ob) {
  const int qb = (int)gridDim.x - 1 - (int)blockIdx.x;  // heavy blocks first
  const int h = blockIdx.y;
  const int b = blockIdx.z;
  const int kv = h >> 2;
  const int t = threadIdx.x;
  const int lane = t & 63;
  const int w = t >> 6;          // 0..7
  const int q = lane & 31;       // query (B-col) / key row (A-row) index
  const int hi = lane >> 5;      // 0/1

  __shared__ __align__(16) unsigned short lds_o[8][32][72];

  const unsigned short* Qh = Qb + ((size_t)(b * NHEADS + h)) * SEQ * HDIM;
  const unsigned short* Kh = Kb + ((size_t)(b * NKV + kv)) * SEQ * HDIM;
  const unsigned short* Vh = Vt + ((size_t)(b * NKV + kv)) * HDIM * SEQ;

  const int wq0 = qb * 256 + w * 32;

  // Q B-frags: qf[f] holds Q[wq0+q][f*16 + hi*8 .. +8]   (pre-scaled by 0.125)
  short8 qf[4];
  #pragma unroll
  for (int f = 0; f < 4; ++f)
    qf[f] = *(const short8*)&Qh[(size_t)(wq0 + q) * HDIM + f * 16 + hi * 8];

  f32x16 o0 = {}, o1 = {};            // O^T accumulators, d-blocks 0..31 / 32..63
  float m_run = -1e30f, l_run = 0.f;

  const int nt = wq0 / 32 + 1;
  for (int tt = 0; tt < nt; ++tt) {
    const int kt0 = tt * 32;
    const bool diag = (tt == nt - 1);

    // ---- S^T[key][query] = K Q^T  (4 MFMAs over d) ----
    f32x16 s = {};
    #pragma unroll
    for (int f = 0; f < 4; ++f) {
      short8 kf = *(const short8*)&Kh[(size_t)(kt0 + q) * HDIM + f * 16 + hi * 8];
      s = MFMA32(kf, qf[f], s);
    }

    // ---- mask (diagonal tile only) + row max ----
    float mt = -1e30f;
    if (diag) {
      #pragma unroll
      for (int r = 0; r < 16; ++r) {
        int kl = (r & 3) + 8 * (r >> 2) + 4 * hi;   // key_local for this reg
        float sc = (kl <= q) ? s[r] : -1e30f;
        s[r] = sc;
        mt = fmaxf(mt, sc);
      }
    } else {
      #pragma unroll
      for (int r = 0; r < 16; ++r) mt = fmaxf(mt, s[r]);
    }
    mt = fmaxf(mt, __shfl_xor(mt, 32, 64));   // combine with partner half

    // ---- online softmax ----
    float mn = fmaxf(m_run, mt);
    float alpha = __expf(m_run - mn);
    m_run = mn;
    float ls = 0.f;
    #pragma unroll
    for (int r = 0; r < 16; ++r) {
      float p = __expf(s[r] - mn);
      s[r] = p;
      ls += p;
    }
    ls += __shfl_xor(ls, 32, 64);
    l_run = l_run * alpha + ls;
    #pragma unroll
    for (int r = 0; r < 16; ++r) { o0[r] *= alpha; o1[r] *= alpha; }

    // ---- pack P to bf16 pairs, exchange halves, build P^T B-frags ----
    unsigned int own[8], rcv[8];
    #pragma unroll
    for (int gg = 0; gg < 8; ++gg)
      own[gg] = (unsigned int)f2bf(s[2 * gg]) | ((unsigned int)f2bf(s[2 * gg + 1]) << 16);
    #pragma unroll
    for (int gg = 0; gg < 8; ++gg)
      rcv[gg] = (unsigned int)__shfl_xor((int)own[gg], 32, 64);

    U4S8 pf0, pf1;
    pf0.u4.x = hi ? rcv[2] : own[0];
    pf0.u4.y = hi ? rcv[3] : own[1];
    pf0.u4.z = hi ? own[2] : rcv[0];
    pf0.u4.w = hi ? own[3] : rcv[1];
    pf1.u4.x = hi ? rcv[6] : own[4];
    pf1.u4.y = hi ? rcv[7] : own[5];
    pf1.u4.z = hi ? own[6] : rcv[4];
    pf1.u4.w = hi ? own[7] : rcv[5];

    // ---- O^T += V^T P^T ----
    const unsigned short* vb = &Vh[(size_t)q * SEQ + kt0 + hi * 8];
    short8 vf00 = *(const short8*)(vb);
    short8 vf01 = *(const short8*)(vb + 16);
    short8 vf10 = *(const short8*)(vb + (size_t)32 * SEQ);
    short8 vf11 = *(const short8*)(vb + (size_t)32 * SEQ + 16);
    o0 = MFMA32(vf00, pf0.v, o0);
    o0 = MFMA32(vf01, pf1.v, o0);
    o1 = MFMA32(vf10, pf0.v, o1);
    o1 = MFMA32(vf11, pf1.v, o1);
  }

  // ---- epilogue: normalize, transpose via per-wave LDS, coalesced store ----
  float inv = 1.0f / l_run;
  #pragma unroll
  for (int gg = 0; gg < 8; ++gg) {
    int r = 2 * gg;
    int dl = (r & 3) + 8 * (r >> 2) + 4 * hi;   // d_local of regs r, r+1 (consecutive)
    unsigned int w0 = (unsigned int)f2bf(o0[r] * inv) | ((unsigned int)f2bf(o0[r + 1] * inv) << 16);
    unsigned int w1 = (unsigned int)f2bf(o1[r] * inv) | ((unsigned int)f2bf(o1[r + 1] * inv) << 16);
    *(unsigned int*)&lds_o[w][q][dl] = w0;
    *(unsigned int*)&lds_o[w][q][32 + dl] = w1;
  }
  // per-wave buffer: within-wave ds_write -> ds_read ordering handled by compiler waitcnt
  {
    int row = lane >> 1;
    int ch = (lane & 1) * 32;
    uint4 x0 = *(const uint4*)&lds_o[w][row][ch + 0];
    uint4 x1 = *(const uint4*)&lds_o[w][row][ch + 8];
    uint4 x2 = *(const uint4*)&lds_o[w][row][ch + 16];
    uint4 x3 = *(const uint4*)&lds_o[w][row][ch + 24];
    unsigned short* dst = &Ob[(size_t)(b * SEQ + wq0 + row) * (NHEADS * HDIM) + h * HDIM + ch];
    *(uint4*)(dst + 0)  = x0;
    *(uint4*)(dst + 8)  = x1;
    *(uint4*)(dst + 16) = x2;
    *(uint4*)(dst + 24) = x3;
  }
}

// =====================================================================
// launcher
// =====================================================================
extern "C" void kernel_launch(void* const* d_in, const int* in_sizes, int n_in,
                              void* d_out, int out_size, void* d_ws, size_t ws_size,
                              hipStream_t stream) {
  const float* X  = (const float*)d_in[0];
  const float* Wq = (const float*)d_in[1];
  const float* Wk = (const float*)d_in[2];
  const float* Wv = (const float*)d_in[3];
  const float* Wo = (const float*)d_in[4];
  float* out = (float*)d_out;

  char* ws = (char*)d_ws;
  size_t off = 0;
  auto carve = [&](size_t bytes) -> void* {
    void* p = ws + off;
    off += (bytes + 255) & ~(size_t)255;
    return p;
  };
  float* rope_cos = (float*)carve((size_t)SEQ * 32 * 4);
  float* rope_sin = (float*)carve((size_t)SEQ * 32 * 4);
  unsigned short* Qb0 = (unsigned short*)carve((size_t)NTOK * NHEADS * HDIM * 2);
  unsigned short* Kb0 = (unsigned short*)carve((size_t)NTOK * NKV * HDIM * 2);
  unsigned short* Vb0 = (unsigned short*)carve((size_t)NTOK * NKV * HDIM * 2);
  unsigned short* Qb  = (unsigned short*)carve((size_t)NTOK * NHEADS * HDIM * 2);
  unsigned short* Kb  = (unsigned short*)carve((size_t)NTOK * NKV * HDIM * 2);
  unsigned short* Vt  = (unsigned short*)carve((size_t)NTOK * NKV * HDIM * 2);
  unsigned short* Ob  = (unsigned short*)carve((size_t)NTOK * NHEADS * HDIM * 2);

  rope_table_kernel<<<dim3(256), dim3(256), 0, stream>>>(rope_cos, rope_sin);

  gemm_kernel<false, true><<<dim3((NHEADS * HDIM) / 64, NTOK / 64), dim3(256), 0, stream>>>(
      X, Wq, Qb0, NTOK, NHEADS * HDIM, HIDDEN);
  gemm_kernel<false, true><<<dim3((NKV * HDIM) / 64, NTOK / 64), dim3(256), 0, stream>>>(
      X, Wk, Kb0, NTOK, NKV * HDIM, HIDDEN);
  gemm_kernel<false, true><<<dim3((NKV * HDIM) / 64, NTOK / 64), dim3(256), 0, stream>>>(
      X, Wv, Vb0, NTOK, NKV * HDIM, HIDDEN);

  rope_apply_kernel<<<dim3((NTOK * 40) / 4), dim3(256), 0, stream>>>(
      Qb0, Kb0, rope_cos, rope_sin, Qb, Kb);

  v_pack_kernel<<<dim3((NTOK * NKV * HDIM) / 256), dim3(256), 0, stream>>>(Vb0, Vt);

  flash_kernel<<<dim3(SEQ / 256, NHEADS, BATCH), dim3(512), 0, stream>>>(Qb, Kb, Vt, Ob);

  gemm_kernel<true, false><<<dim3(HIDDEN / 64, NTOK / 64), dim3(256), 0, stream>>>(
      Ob, Wo, out, NTOK, HIDDEN, HIDDEN);
}

// Round 3
// 398.692 us; speedup vs baseline: 2.6115x; 1.9158x over previous
//
#include <hip/hip_runtime.h>
#include <cstdint>
#include <cstddef>

// ---------- types ----------
typedef __attribute__((ext_vector_type(8))) short short8;   // 8 bf16 MFMA A/B frag
typedef __attribute__((ext_vector_type(4))) float f32x4;    // 16x16 C/D frag
typedef __attribute__((ext_vector_type(16))) float f32x16;  // 32x32 C/D frag

#define MFMA16(a, b, c) __builtin_amdgcn_mfma_f32_16x16x32_bf16((a), (b), (c), 0, 0, 0)
#define MFMA32(a, b, c) __builtin_amdgcn_mfma_f32_32x32x16_bf16((a), (b), (c), 0, 0, 0)

union F2U { float f; unsigned int u; };
union U4S8 { uint4 u4; unsigned short s[8]; short8 v; };

__device__ __forceinline__ unsigned short f2bf(float f) {
  F2U x; x.f = f;
  unsigned int r = x.u + 0x7fffu + ((x.u >> 16) & 1u);  // RNE
  return (unsigned short)(r >> 16);
}
__device__ __forceinline__ float bf2f(unsigned short s) {
  F2U x; x.u = ((unsigned int)s) << 16;
  return x.f;
}

// ---------- problem constants ----------
#define HIDDEN 2048
#define NHEADS 32
#define NKV 8
#define HDIM 64
#define SEQ 2048
#define BATCH 2
#define NTOK (BATCH * SEQ)   // 4096
#define QKVN 3072            // fused QKV output width (2048 Q | 512 K | 512 V)

// =====================================================================
// RoPE table: cos/sin [SEQ][32] fp32
// =====================================================================
__global__ __launch_bounds__(256) void rope_table_kernel(float* __restrict__ ct, float* __restrict__ st) {
  int idx = blockIdx.x * 256 + threadIdx.x;     // 0 .. 65535
  int s = idx >> 5;
  int i = idx & 31;
  float invf = expf(-(float)i * (9.210340371976184f / 32.0f));  // 10000^(-i/32)
  float f = (float)s * invf;
  ct[idx] = cosf(f);
  st[idx] = sinf(f);
}

// =====================================================================
// X fp32 -> bf16 (elementwise, vectorized)
// =====================================================================
__global__ __launch_bounds__(256) void convert_x_kernel(const float* __restrict__ X,
                                                        unsigned short* __restrict__ Xb) {
  size_t i = ((size_t)blockIdx.x * 256 + threadIdx.x) * 8;
  float4 a0 = *(const float4*)(X + i);
  float4 a1 = *(const float4*)(X + i + 4);
  U4S8 p;
  p.s[0] = f2bf(a0.x); p.s[1] = f2bf(a0.y); p.s[2] = f2bf(a0.z); p.s[3] = f2bf(a0.w);
  p.s[4] = f2bf(a1.x); p.s[5] = f2bf(a1.y); p.s[6] = f2bf(a1.z); p.s[7] = f2bf(a1.w);
  *(short8*)(Xb + i) = p.v;
}

// =====================================================================
// Weight transpose+convert: W [K=2048][N] fp32 -> Wt[row_off + n][k] bf16
// (dst leading dim HIDDEN). 64x64 tiles via LDS.
// =====================================================================
__global__ __launch_bounds__(256) void transpose_w_kernel(const float* __restrict__ W,
                                                          unsigned short* __restrict__ Wt,
                                                          int N, int row_off) {
  __shared__ unsigned short lt[64][72];  // [n][k], padded
  const int t = threadIdx.x;
  const int k0 = blockIdx.y * 64, n0 = blockIdx.x * 64;
  #pragma unroll
  for (int p = 0; p < 4; ++p) {
    int kr = p * 16 + (t >> 4);
    int nc = (t & 15) * 4;
    float4 v = *(const float4*)&W[(size_t)(k0 + kr) * N + n0 + nc];
    lt[nc + 0][kr] = f2bf(v.x);
    lt[nc + 1][kr] = f2bf(v.y);
    lt[nc + 2][kr] = f2bf(v.z);
    lt[nc + 3][kr] = f2bf(v.w);
  }
  __syncthreads();
  #pragma unroll
  for (int p = 0; p < 2; ++p) {
    int nr = p * 32 + (t >> 3);
    int kc = (t & 7) * 8;
    *(short8*)&Wt[(size_t)(row_off + n0 + nr) * HIDDEN + k0 + kc] = *(const short8*)&lt[nr][kc];
  }
}

// =====================================================================
// GEMM (m97-class): C[M,N] = A[M,K] @ Bt[N,K]^T, all bf16 operands.
// 128x128 tile, BK=64, 256 threads = 4 waves (2x2 of 64x64).
// Staging via global_load_lds width 16 with XOR chunk swizzle:
//   linear LDS dest, source chunk = (lane&7) ^ (row&7), read chunk ^ (row&7).
// =====================================================================
template<bool OUT_BF16>
__global__ __launch_bounds__(256) void gemm128_kernel(const unsigned short* __restrict__ Ab,
                                                      const unsigned short* __restrict__ Bt,
                                                      void* __restrict__ Cp,
                                                      int M, int N, int K) {
  __shared__ __align__(16) unsigned short lds_a[128][64];
  __shared__ __align__(16) unsigned short lds_b[128][64];

  const int t = threadIdx.x, lane = t & 63, w = t >> 6;
  const int lr = lane & 15, lh = lane >> 4;
  const int m0 = blockIdx.y * 128, n0 = blockIdx.x * 128;
  const int wr = (w >> 1) * 64, wc = (w & 1) * 64;

  f32x4 acc[4][4] = {};

  for (int k0 = 0; k0 < K; k0 += 64) {
    __syncthreads();
    #pragma unroll
    for (int c = 0; c < 4; ++c) {
      int row = w * 32 + c * 8 + (lane >> 3);          // tile-local row this lane feeds
      int cks = (lane & 7) ^ (row & 7);                // inverse-swizzled source chunk
      __builtin_amdgcn_global_load_lds(
          (const __attribute__((address_space(1))) unsigned int*)(Ab + (size_t)(m0 + row) * K + k0 + cks * 8),
          (__attribute__((address_space(3))) unsigned int*)&lds_a[w * 32 + c * 8][0], 16, 0, 0);
      __builtin_amdgcn_global_load_lds(
          (const __attribute__((address_space(1))) unsigned int*)(Bt + (size_t)(n0 + row) * K + k0 + cks * 8),
          (__attribute__((address_space(3))) unsigned int*)&lds_b[w * 32 + c * 8][0], 16, 0, 0);
    }
    __syncthreads();   // compiler drains vmcnt before barrier

    #pragma unroll
    for (int kk = 0; kk < 2; ++kk) {
      short8 af[4], bf[4];
      #pragma unroll
      for (int i = 0; i < 4; ++i) {
        int row = wr + i * 16 + lr;
        af[i] = *(const short8*)((const char*)&lds_a[0][0] + row * 128 + (((kk * 4 + lh) ^ (row & 7)) * 16));
      }
      #pragma unroll
      for (int j = 0; j < 4; ++j) {
        int row = wc + j * 16 + lr;
        bf[j] = *(const short8*)((const char*)&lds_b[0][0] + row * 128 + (((kk * 4 + lh) ^ (row & 7)) * 16));
      }
      #pragma unroll
      for (int i = 0; i < 4; ++i)
        #pragma unroll
        for (int j = 0; j < 4; ++j)
          acc[i][j] = MFMA16(af[i], bf[j], acc[i][j]);
    }
  }

  // epilogue: D layout col = lane&15, row = (lane>>4)*4 + reg
  #pragma unroll
  for (int i = 0; i < 4; ++i)
    #pragma unroll
    for (int j = 0; j < 4; ++j)
      #pragma unroll
      for (int r = 0; r < 4; ++r) {
        int row = m0 + wr + i * 16 + lh * 4 + r;
        int col = n0 + wc + j * 16 + lr;
        if constexpr (OUT_BF16)
          ((unsigned short*)Cp)[(size_t)row * N + col] = f2bf(acc[i][j][r]);
        else
          ((float*)Cp)[(size_t)row * N + col] = acc[i][j][r];
      }
}

// =====================================================================
// RoPE apply IN-PLACE on QKVb [4096][3072]; Q cols h*64, K cols 2048+h2*64.
// Q additionally pre-scaled by 1/sqrt(HDIM) = 0.125.
// =====================================================================
__global__ __launch_bounds__(256) void rope_apply_kernel(unsigned short* __restrict__ QKV,
                                                         const float* __restrict__ ct,
                                                         const float* __restrict__ st) {
  int uid = blockIdx.x * 4 + (threadIdx.x >> 6);
  int d = threadIdx.x & 63;
  int m = uid / 40;
  int hh = uid - m * 40;
  int s = m & 2047;

  unsigned short* p = QKV + (size_t)m * QKVN + (hh < 32 ? hh * 64 : 2048 + (hh - 32) * 64);
  float v = bf2f(p[d]);
  float pr = __shfl_xor(v, 32, 64);       // partner element d^32
  int fi = d & 31;
  float c = ct[s * 32 + fi];
  float sn = st[s * 32 + fi];
  float sgn = (d < 32) ? -1.0f : 1.0f;    // rotate_half: [-x2, x1]
  float o = v * c + sgn * pr * sn;
  if (hh < 32) o *= 0.125f;
  p[d] = f2bf(o);
}

// =====================================================================
// V pack/transpose: QKVb cols 2560.. -> Vt [B][KV][64][S] bf16
// =====================================================================
__global__ __launch_bounds__(256) void v_pack_kernel(const unsigned short* __restrict__ QKV,
                                                     unsigned short* __restrict__ Vt) {
  int idx = blockIdx.x * 256 + threadIdx.x;  // 0 .. 2M-1
  int m = idx >> 9;
  int c = idx & 511;
  int b = m >> 11, s = m & 2047;
  int kv = c >> 6, d = c & 63;
  Vt[(((size_t)(b * NKV + kv)) * HDIM + d) * SEQ + s] = QKV[(size_t)m * QKVN + 2560 + c];
}

// =====================================================================
// Flash attention, 8-wave 32x32 swapped-QK^T (unchanged structure);
// Q/K read strided (QKVN) directly from QKVb.
// =====================================================================
__global__ __launch_bounds__(512) void flash_kernel(const unsigned short* __restrict__ QKV,
                                                    const unsigned short* __restrict__ Vt,
                                                    unsigned short* __restrict__ Ob) {
  const int qb = (int)gridDim.x - 1 - (int)blockIdx.x;  // heavy blocks first
  const int h = blockIdx.y;
  const int b = blockIdx.z;
  const int kv = h >> 2;
  const int t = threadIdx.x;
  const int lane = t & 63;
  const int w = t >> 6;          // 0..7
  const int q = lane & 31;
  const int hi = lane >> 5;

  __shared__ __align__(16) unsigned short lds_o[8][32][72];

  const unsigned short* Qh = QKV + (size_t)b * SEQ * QKVN + h * 64;
  const unsigned short* Kh = QKV + (size_t)b * SEQ * QKVN + 2048 + kv * 64;
  const unsigned short* Vh = Vt + ((size_t)(b * NKV + kv)) * HDIM * SEQ;

  const int wq0 = qb * 256 + w * 32;

  short8 qf[4];
  #pragma unroll
  for (int f = 0; f < 4; ++f)
    qf[f] = *(const short8*)&Qh[(size_t)(wq0 + q) * QKVN + f * 16 + hi * 8];

  f32x16 o0 = {}, o1 = {};
  float m_run = -1e30f, l_run = 0.f;

  const int nt = wq0 / 32 + 1;
  for (int tt = 0; tt < nt; ++tt) {
    const int kt0 = tt * 32;
    const bool diag = (tt == nt - 1);

    f32x16 s = {};
    #pragma unroll
    for (int f = 0; f < 4; ++f) {
      short8 kf = *(const short8*)&Kh[(size_t)(kt0 + q) * QKVN + f * 16 + hi * 8];
      s = MFMA32(kf, qf[f], s);
    }

    float mt = -1e30f;
    if (diag) {
      #pragma unroll
      for (int r = 0; r < 16; ++r) {
        int kl = (r & 3) + 8 * (r >> 2) + 4 * hi;
        float sc = (kl <= q) ? s[r] : -1e30f;
        s[r] = sc;
        mt = fmaxf(mt, sc);
      }
    } else {
      #pragma unroll
      for (int r = 0; r < 16; ++r) mt = fmaxf(mt, s[r]);
    }
    mt = fmaxf(mt, __shfl_xor(mt, 32, 64));

    float mn = fmaxf(m_run, mt);
    float alpha = __expf(m_run - mn);
    m_run = mn;
    float ls = 0.f;
    #pragma unroll
    for (int r = 0; r < 16; ++r) {
      float p = __expf(s[r] - mn);
      s[r] = p;
      ls += p;
    }
    ls += __shfl_xor(ls, 32, 64);
    l_run = l_run * alpha + ls;
    #pragma unroll
    for (int r = 0; r < 16; ++r) { o0[r] *= alpha; o1[r] *= alpha; }

    unsigned int own[8], rcv[8];
    #pragma unroll
    for (int gg = 0; gg < 8; ++gg)
      own[gg] = (unsigned int)f2bf(s[2 * gg]) | ((unsigned int)f2bf(s[2 * gg + 1]) << 16);
    #pragma unroll
    for (int gg = 0; gg < 8; ++gg)
      rcv[gg] = (unsigned int)__shfl_xor((int)own[gg], 32, 64);

    U4S8 pf0, pf1;
    pf0.u4.x = hi ? rcv[2] : own[0];
    pf0.u4.y = hi ? rcv[3] : own[1];
    pf0.u4.z = hi ? own[2] : rcv[0];
    pf0.u4.w = hi ? own[3] : rcv[1];
    pf1.u4.x = hi ? rcv[6] : own[4];
    pf1.u4.y = hi ? rcv[7] : own[5];
    pf1.u4.z = hi ? own[6] : rcv[4];
    pf1.u4.w = hi ? own[7] : rcv[5];

    const unsigned short* vb = &Vh[(size_t)q * SEQ + kt0 + hi * 8];
    short8 vf00 = *(const short8*)(vb);
    short8 vf01 = *(const short8*)(vb + 16);
    short8 vf10 = *(const short8*)(vb + (size_t)32 * SEQ);
    short8 vf11 = *(const short8*)(vb + (size_t)32 * SEQ + 16);
    o0 = MFMA32(vf00, pf0.v, o0);
    o0 = MFMA32(vf01, pf1.v, o0);
    o1 = MFMA32(vf10, pf0.v, o1);
    o1 = MFMA32(vf11, pf1.v, o1);
  }

  float inv = 1.0f / l_run;
  #pragma unroll
  for (int gg = 0; gg < 8; ++gg) {
    int r = 2 * gg;
    int dl = (r & 3) + 8 * (r >> 2) + 4 * hi;
    unsigned int w0 = (unsigned int)f2bf(o0[r] * inv) | ((unsigned int)f2bf(o0[r + 1] * inv) << 16);
    unsigned int w1 = (unsigned int)f2bf(o1[r] * inv) | ((unsigned int)f2bf(o1[r + 1] * inv) << 16);
    *(unsigned int*)&lds_o[w][q][dl] = w0;
    *(unsigned int*)&lds_o[w][q][32 + dl] = w1;
  }
  {
    int row = lane >> 1;
    int ch = (lane & 1) * 32;
    uint4 x0 = *(const uint4*)&lds_o[w][row][ch + 0];
    uint4 x1 = *(const uint4*)&lds_o[w][row][ch + 8];
    uint4 x2 = *(const uint4*)&lds_o[w][row][ch + 16];
    uint4 x3 = *(const uint4*)&lds_o[w][row][ch + 24];
    unsigned short* dst = &Ob[(size_t)(b * SEQ + wq0 + row) * (NHEADS * HDIM) + h * HDIM + ch];
    *(uint4*)(dst + 0)  = x0;
    *(uint4*)(dst + 8)  = x1;
    *(uint4*)(dst + 16) = x2;
    *(uint4*)(dst + 24) = x3;
  }
}

// =====================================================================
// launcher
// =====================================================================
extern "C" void kernel_launch(void* const* d_in, const int* in_sizes, int n_in,
                              void* d_out, int out_size, void* d_ws, size_t ws_size,
                              hipStream_t stream) {
  const float* X  = (const float*)d_in[0];
  const float* Wq = (const float*)d_in[1];
  const float* Wk = (const float*)d_in[2];
  const float* Wv = (const float*)d_in[3];
  const float* Wo = (const float*)d_in[4];
  float* out = (float*)d_out;

  char* ws = (char*)d_ws;
  size_t off = 0;
  auto carve = [&](size_t bytes) -> void* {
    void* p = ws + off;
    off += (bytes + 255) & ~(size_t)255;
    return p;
  };
  float* rope_cos = (float*)carve((size_t)SEQ * 32 * 4);
  float* rope_sin = (float*)carve((size_t)SEQ * 32 * 4);
  unsigned short* Xb     = (unsigned short*)carve((size_t)NTOK * HIDDEN * 2);   // also reused as Ob
  unsigned short* Wqkv_t = (unsigned short*)carve((size_t)QKVN * HIDDEN * 2);
  unsigned short* Wot    = (unsigned short*)carve((size_t)HIDDEN * HIDDEN * 2);
  unsigned short* QKVb   = (unsigned short*)carve((size_t)NTOK * QKVN * 2);
  unsigned short* Vt     = (unsigned short*)carve((size_t)BATCH * NKV * HDIM * SEQ * 2);
  unsigned short* Ob     = Xb;   // Xb dead after QKV GEMM

  rope_table_kernel<<<dim3(256), dim3(256), 0, stream>>>(rope_cos, rope_sin);
  convert_x_kernel<<<dim3((NTOK * HIDDEN) / (256 * 8)), dim3(256), 0, stream>>>(X, Xb);

  transpose_w_kernel<<<dim3(2048 / 64, HIDDEN / 64), dim3(256), 0, stream>>>(Wq, Wqkv_t, 2048, 0);
  transpose_w_kernel<<<dim3(512 / 64,  HIDDEN / 64), dim3(256), 0, stream>>>(Wk, Wqkv_t, 512, 2048);
  transpose_w_kernel<<<dim3(512 / 64,  HIDDEN / 64), dim3(256), 0, stream>>>(Wv, Wqkv_t, 512, 2560);
  transpose_w_kernel<<<dim3(2048 / 64, HIDDEN / 64), dim3(256), 0, stream>>>(Wo, Wot, 2048, 0);

  gemm128_kernel<true><<<dim3(QKVN / 128, NTOK / 128), dim3(256), 0, stream>>>(
      Xb, Wqkv_t, QKVb, NTOK, QKVN, HIDDEN);

  rope_apply_kernel<<<dim3((NTOK * 40) / 4), dim3(256), 0, stream>>>(QKVb, rope_cos, rope_sin);
  v_pack_kernel<<<dim3((NTOK * NKV * HDIM) / 256), dim3(256), 0, stream>>>(QKVb, Vt);

  flash_kernel<<<dim3(SEQ / 256, NHEADS, BATCH), dim3(512), 0, stream>>>(QKVb, Vt, Ob);

  gemm128_kernel<false><<<dim3(HIDDEN / 128, NTOK / 128), dim3(256), 0, stream>>>(
      Ob, Wot, out, NTOK, HIDDEN, HIDDEN);
}

// Round 4
// 373.046 us; speedup vs baseline: 2.7910x; 1.0687x over previous
//
#include <hip/hip_runtime.h>
#include <cstdint>
#include <cstddef>

// ---------- types ----------
typedef __attribute__((ext_vector_type(8))) short short8;   // 8 bf16 MFMA A/B frag
typedef __attribute__((ext_vector_type(4))) float f32x4;    // 16x16 C/D frag
typedef __attribute__((ext_vector_type(16))) float f32x16;  // 32x32 C/D frag

#define MFMA16(a, b, c) __builtin_amdgcn_mfma_f32_16x16x32_bf16((a), (b), (c), 0, 0, 0)
#define MFMA32(a, b, c) __builtin_amdgcn_mfma_f32_32x32x16_bf16((a), (b), (c), 0, 0, 0)

union F2U { float f; unsigned int u; };
union U4S8 { uint4 u4; unsigned short s[8]; short8 v; };

__device__ __forceinline__ unsigned short f2bf(float f) {
  F2U x; x.f = f;
  unsigned int r = x.u + 0x7fffu + ((x.u >> 16) & 1u);  // RNE
  return (unsigned short)(r >> 16);
}
__device__ __forceinline__ float bf2f(unsigned short s) {
  F2U x; x.u = ((unsigned int)s) << 16;
  return x.f;
}

// ---------- problem constants ----------
#define HIDDEN 2048
#define NHEADS 32
#define NKV 8
#define HDIM 64
#define SEQ 2048
#define BATCH 2
#define NTOK (BATCH * SEQ)   // 4096
#define QKVN 3072            // fused QKV output width (2048 Q | 512 K | 512 V)

// =====================================================================
// RoPE table: cos/sin [SEQ][32] fp32
// =====================================================================
__global__ __launch_bounds__(256) void rope_table_kernel(float* __restrict__ ct, float* __restrict__ st) {
  int idx = blockIdx.x * 256 + threadIdx.x;     // 0 .. 65535
  int s = idx >> 5;
  int i = idx & 31;
  float invf = expf(-(float)i * (9.210340371976184f / 32.0f));  // 10000^(-i/32)
  float f = (float)s * invf;
  ct[idx] = cosf(f);
  st[idx] = sinf(f);
}

// =====================================================================
// X fp32 -> bf16 (elementwise, vectorized)
// =====================================================================
__global__ __launch_bounds__(256) void convert_x_kernel(const float* __restrict__ X,
                                                        unsigned short* __restrict__ Xb) {
  size_t i = ((size_t)blockIdx.x * 256 + threadIdx.x) * 8;
  float4 a0 = *(const float4*)(X + i);
  float4 a1 = *(const float4*)(X + i + 4);
  U4S8 p;
  p.s[0] = f2bf(a0.x); p.s[1] = f2bf(a0.y); p.s[2] = f2bf(a0.z); p.s[3] = f2bf(a0.w);
  p.s[4] = f2bf(a1.x); p.s[5] = f2bf(a1.y); p.s[6] = f2bf(a1.z); p.s[7] = f2bf(a1.w);
  *(short8*)(Xb + i) = p.v;
}

// =====================================================================
// Weight transpose+convert: W [K=2048][N] fp32 -> Wt[row_off + n][k] bf16
// =====================================================================
__global__ __launch_bounds__(256) void transpose_w_kernel(const float* __restrict__ W,
                                                          unsigned short* __restrict__ Wt,
                                                          int N, int row_off) {
  __shared__ unsigned short lt[64][72];  // [n][k], padded
  const int t = threadIdx.x;
  const int k0 = blockIdx.y * 64, n0 = blockIdx.x * 64;
  #pragma unroll
  for (int p = 0; p < 4; ++p) {
    int kr = p * 16 + (t >> 4);
    int nc = (t & 15) * 4;
    float4 v = *(const float4*)&W[(size_t)(k0 + kr) * N + n0 + nc];
    lt[nc + 0][kr] = f2bf(v.x);
    lt[nc + 1][kr] = f2bf(v.y);
    lt[nc + 2][kr] = f2bf(v.z);
    lt[nc + 3][kr] = f2bf(v.w);
  }
  __syncthreads();
  #pragma unroll
  for (int p = 0; p < 2; ++p) {
    int nr = p * 32 + (t >> 3);
    int kc = (t & 7) * 8;
    *(short8*)&Wt[(size_t)(row_off + n0 + nr) * HIDDEN + k0 + kc] = *(const short8*)&lt[nr][kc];
  }
}

// =====================================================================
// GEMM (m97-class): C[M,N] = A[M,K] @ Bt[N,K]^T, all bf16 operands.
// 128x128 tile, BK=64, 4 waves; global_load_lds w16 + XOR chunk swizzle.
// =====================================================================
template<bool OUT_BF16>
__global__ __launch_bounds__(256) void gemm128_kernel(const unsigned short* __restrict__ Ab,
                                                      const unsigned short* __restrict__ Bt,
                                                      void* __restrict__ Cp,
                                                      int M, int N, int K) {
  __shared__ __align__(16) unsigned short lds_a[128][64];
  __shared__ __align__(16) unsigned short lds_b[128][64];

  const int t = threadIdx.x, lane = t & 63, w = t >> 6;
  const int lr = lane & 15, lh = lane >> 4;
  const int m0 = blockIdx.y * 128, n0 = blockIdx.x * 128;
  const int wr = (w >> 1) * 64, wc = (w & 1) * 64;

  f32x4 acc[4][4] = {};

  for (int k0 = 0; k0 < K; k0 += 64) {
    __syncthreads();
    #pragma unroll
    for (int c = 0; c < 4; ++c) {
      int row = w * 32 + c * 8 + (lane >> 3);
      int cks = (lane & 7) ^ (row & 7);
      __builtin_amdgcn_global_load_lds(
          (const __attribute__((address_space(1))) unsigned int*)(Ab + (size_t)(m0 + row) * K + k0 + cks * 8),
          (__attribute__((address_space(3))) unsigned int*)&lds_a[w * 32 + c * 8][0], 16, 0, 0);
      __builtin_amdgcn_global_load_lds(
          (const __attribute__((address_space(1))) unsigned int*)(Bt + (size_t)(n0 + row) * K + k0 + cks * 8),
          (__attribute__((address_space(3))) unsigned int*)&lds_b[w * 32 + c * 8][0], 16, 0, 0);
    }
    __syncthreads();

    #pragma unroll
    for (int kk = 0; kk < 2; ++kk) {
      short8 af[4], bf[4];
      #pragma unroll
      for (int i = 0; i < 4; ++i) {
        int row = wr + i * 16 + lr;
        af[i] = *(const short8*)((const char*)&lds_a[0][0] + row * 128 + (((kk * 4 + lh) ^ (row & 7)) * 16));
      }
      #pragma unroll
      for (int j = 0; j < 4; ++j) {
        int row = wc + j * 16 + lr;
        bf[j] = *(const short8*)((const char*)&lds_b[0][0] + row * 128 + (((kk * 4 + lh) ^ (row & 7)) * 16));
      }
      #pragma unroll
      for (int i = 0; i < 4; ++i)
        #pragma unroll
        for (int j = 0; j < 4; ++j)
          acc[i][j] = MFMA16(af[i], bf[j], acc[i][j]);
    }
  }

  #pragma unroll
  for (int i = 0; i < 4; ++i)
    #pragma unroll
    for (int j = 0; j < 4; ++j)
      #pragma unroll
      for (int r = 0; r < 4; ++r) {
        int row = m0 + wr + i * 16 + lh * 4 + r;
        int col = n0 + wc + j * 16 + lr;
        if constexpr (OUT_BF16)
          ((unsigned short*)Cp)[(size_t)row * N + col] = f2bf(acc[i][j][r]);
        else
          ((float*)Cp)[(size_t)row * N + col] = acc[i][j][r];
      }
}

// =====================================================================
// RoPE apply IN-PLACE on QKVb [4096][3072]; Q pre-scaled by 0.125.
// =====================================================================
__global__ __launch_bounds__(256) void rope_apply_kernel(unsigned short* __restrict__ QKV,
                                                         const float* __restrict__ ct,
                                                         const float* __restrict__ st) {
  int uid = blockIdx.x * 4 + (threadIdx.x >> 6);
  int d = threadIdx.x & 63;
  int m = uid / 40;
  int hh = uid - m * 40;
  int s = m & 2047;

  unsigned short* p = QKV + (size_t)m * QKVN + (hh < 32 ? hh * 64 : 2048 + (hh - 32) * 64);
  float v = bf2f(p[d]);
  float pr = __shfl_xor(v, 32, 64);
  int fi = d & 31;
  float c = ct[s * 32 + fi];
  float sn = st[s * 32 + fi];
  float sgn = (d < 32) ? -1.0f : 1.0f;
  float o = v * c + sgn * pr * sn;
  if (hh < 32) o *= 0.125f;
  p[d] = f2bf(o);
}

// =====================================================================
// V pack/transpose: QKVb cols 2560.. -> Vt [B][KV][64][S] bf16
// =====================================================================
__global__ __launch_bounds__(256) void v_pack_kernel(const unsigned short* __restrict__ QKV,
                                                     unsigned short* __restrict__ Vt) {
  int idx = blockIdx.x * 256 + threadIdx.x;
  int m = idx >> 9;
  int c = idx & 511;
  int b = m >> 11, s = m & 2047;
  int kv = c >> 6, d = c & 63;
  Vt[(((size_t)(b * NKV + kv)) * HDIM + d) * SEQ + s] = QKV[(size_t)m * QKVN + 2560 + c];
}

// =====================================================================
// Flash attention: 8 waves x 32 q-rows, KVBLK=64, cooperative K/V LDS
// staging (double-buffered, XOR-swizzled, global_load_lds w16), swapped
// QK^T 32x32 MFMA, in-register softmax. One barrier per KV tile.
// =====================================================================
#define KVBLK 64

__global__ __launch_bounds__(512, 4) void flash_kernel(const unsigned short* __restrict__ QKV,
                                                       const unsigned short* __restrict__ Vt,
                                                       unsigned short* __restrict__ Ob) {
  const int qb = (int)gridDim.x - 1 - (int)blockIdx.x;  // heavy blocks first
  const int h = blockIdx.y;
  const int b = blockIdx.z;
  const int kv = h >> 2;
  const int t = threadIdx.x;
  const int lane = t & 63;
  const int w = t >> 6;          // 0..7
  const int q = lane & 31;
  const int hi = lane >> 5;

  // [0,16384): K dbuf [2][64][64] bf16 ; [16384,32768): V dbuf [2][64][64]
  // epilogue: whole region reused as per-wave transpose buffers [8][32][72]
  __shared__ __align__(16) char smem[36864];
  unsigned short* Klds = (unsigned short*)smem;
  unsigned short* Vlds = (unsigned short*)(smem + 16384);

  const unsigned short* Kg = QKV + (size_t)b * SEQ * QKVN + 2048 + kv * 64;
  const unsigned short* Vg = Vt + ((size_t)(b * NKV + kv)) * HDIM * SEQ;

  const int wq0 = qb * 256 + w * 32;

  // Q B-frags (pre-scaled by 0.125): qf[f] = Q[wq0+q][f*16+hi*8 ..]
  const unsigned short* Qh = QKV + (size_t)b * SEQ * QKVN + h * 64;
  short8 qf[4];
  #pragma unroll
  for (int f = 0; f < 4; ++f)
    qf[f] = *(const short8*)&Qh[(size_t)(wq0 + q) * QKVN + f * 16 + hi * 8];

  // staging: wave w covers rows [w*8, w*8+8); lane l -> row w*8+(l>>3),
  // chunk slot l&7; source chunk inverse-swizzled so read-side XOR works.
  const int srow = w * 8 + (lane >> 3);
  const int scks = (lane & 7) ^ (srow & 7);
  const unsigned short* Ksrc = Kg + (size_t)srow * QKVN + scks * 8;   // + (kt0)*QKVN
  const unsigned short* Vsrc = Vg + (size_t)srow * SEQ + scks * 8;    // + kt0

  #define STAGE_KV(buf, kt0)                                                              \
    do {                                                                                  \
      __builtin_amdgcn_global_load_lds(                                                   \
          (const __attribute__((address_space(1))) unsigned int*)(Ksrc + (size_t)(kt0) * QKVN), \
          (__attribute__((address_space(3))) unsigned int*)(Klds + (buf) * 4096 + w * 512), 16, 0, 0); \
      __builtin_amdgcn_global_load_lds(                                                   \
          (const __attribute__((address_space(1))) unsigned int*)(Vsrc + (kt0)),          \
          (__attribute__((address_space(3))) unsigned int*)(Vlds + (buf) * 4096 + w * 512), 16, 0, 0); \
    } while (0)

  f32x16 o0 = {}, o1 = {};
  float m_run = -1e30f, l_run = 0.f;

  const int nt_blk = qb * 4 + 4;            // tiles staged by the block
  const int nt_w   = qb * 4 + (w >> 1) + 1; // tiles this wave computes

  STAGE_KV(0, 0);
  __syncthreads();
  int cur = 0;

  for (int tt = 0; tt < nt_blk; ++tt) {
    if (tt + 1 < nt_blk) STAGE_KV(cur ^ 1, (tt + 1) * KVBLK);

    if (tt < nt_w) {
      const int kt0 = tt * KVBLK;
      const bool diag = (tt == nt_w - 1);
      const unsigned short* Kt = Klds + cur * 4096;
      const unsigned short* Vl = Vlds + cur * 4096;

      // ---- S^T = K Q^T : two 32-key halves ----
      f32x16 s0v = {}, s1v = {};
      __builtin_amdgcn_s_setprio(1);
      #pragma unroll
      for (int f = 0; f < 4; ++f) {
        int co = ((f * 2 + hi) ^ (q & 7)) * 8;
        short8 kf0 = *(const short8*)(Kt + q * 64 + co);
        short8 kf1 = *(const short8*)(Kt + (32 + q) * 64 + co);
        s0v = MFMA32(kf0, qf[f], s0v);
        s1v = MFMA32(kf1, qf[f], s1v);
      }
      __builtin_amdgcn_s_setprio(0);

      // ---- causal mask (last tile for this wave only) ----
      if (diag) {
        #pragma unroll
        for (int r = 0; r < 16; ++r) {
          int kl = (r & 3) + 8 * (r >> 2) + 4 * hi;
          if (kt0 + kl > wq0 + q) s0v[r] = -1e30f;
          if (kt0 + 32 + kl > wq0 + q) s1v[r] = -1e30f;
        }
      }

      // ---- row max ----
      float mt = -1e30f;
      #pragma unroll
      for (int r = 0; r < 16; ++r) mt = fmaxf(mt, fmaxf(s0v[r], s1v[r]));
      mt = fmaxf(mt, __shfl_xor(mt, 32, 64));

      // ---- online softmax ----
      float mn = fmaxf(m_run, mt);
      float alpha = __expf(m_run - mn);
      m_run = mn;
      float ls = 0.f;
      #pragma unroll
      for (int r = 0; r < 16; ++r) {
        float p0 = __expf(s0v[r] - mn);
        float p1 = __expf(s1v[r] - mn);
        s0v[r] = p0; s1v[r] = p1;
        ls += p0 + p1;
      }
      ls += __shfl_xor(ls, 32, 64);
      l_run = l_run * alpha + ls;
      #pragma unroll
      for (int r = 0; r < 16; ++r) { o0[r] *= alpha; o1[r] *= alpha; }

      // ---- pack P -> bf16 words, exchange halves ----
      unsigned int own0[8], own1[8], rcv0[8], rcv1[8];
      #pragma unroll
      for (int g = 0; g < 8; ++g) {
        own0[g] = (unsigned int)f2bf(s0v[2 * g]) | ((unsigned int)f2bf(s0v[2 * g + 1]) << 16);
        own1[g] = (unsigned int)f2bf(s1v[2 * g]) | ((unsigned int)f2bf(s1v[2 * g + 1]) << 16);
      }
      #pragma unroll
      for (int g = 0; g < 8; ++g) {
        rcv0[g] = (unsigned int)__shfl_xor((int)own0[g], 32, 64);
        rcv1[g] = (unsigned int)__shfl_xor((int)own1[g], 32, 64);
      }

      // ---- build P^T B-frags: ks=0..3 (16 keys each) ----
      U4S8 pf[4];
      #pragma unroll
      for (int ks = 0; ks < 4; ++ks) {
        const unsigned int* ow = (ks >> 1) ? own1 : own0;
        const unsigned int* rc = (ks >> 1) ? rcv1 : rcv0;
        int w0 = 4 * (ks & 1) + 2 * hi;
        pf[ks].u4.x = hi ? rc[w0]     : ow[w0];
        pf[ks].u4.y = hi ? rc[w0 + 1] : ow[w0 + 1];
        pf[ks].u4.z = hi ? ow[w0]     : rc[w0];
        pf[ks].u4.w = hi ? ow[w0 + 1] : rc[w0 + 1];
      }

      // ---- O^T += V^T P^T ----
      __builtin_amdgcn_s_setprio(1);
      #pragma unroll
      for (int ks = 0; ks < 4; ++ks) {
        int co = ((ks * 2 + hi) ^ (q & 7)) * 8;
        short8 vf0 = *(const short8*)(Vl + q * 64 + co);
        short8 vf1 = *(const short8*)(Vl + (32 + q) * 64 + co);
        o0 = MFMA32(vf0, pf[ks].v, o0);
        o1 = MFMA32(vf1, pf[ks].v, o1);
      }
      __builtin_amdgcn_s_setprio(0);
    }

    __syncthreads();
    cur ^= 1;
  }

  // ---- epilogue: normalize, per-wave LDS transpose (aliases K/V), store ----
  unsigned short* lo = (unsigned short*)smem + (size_t)w * 32 * 72;
  float inv = 1.0f / l_run;
  #pragma unroll
  for (int gg = 0; gg < 8; ++gg) {
    int r = 2 * gg;
    int dl = (r & 3) + 8 * (r >> 2) + 4 * hi;
    unsigned int w0 = (unsigned int)f2bf(o0[r] * inv) | ((unsigned int)f2bf(o0[r + 1] * inv) << 16);
    unsigned int w1 = (unsigned int)f2bf(o1[r] * inv) | ((unsigned int)f2bf(o1[r + 1] * inv) << 16);
    *(unsigned int*)&lo[q * 72 + dl] = w0;
    *(unsigned int*)&lo[q * 72 + 32 + dl] = w1;
  }
  {
    int row = lane >> 1;
    int ch = (lane & 1) * 32;
    uint4 x0 = *(const uint4*)&lo[row * 72 + ch + 0];
    uint4 x1 = *(const uint4*)&lo[row * 72 + ch + 8];
    uint4 x2 = *(const uint4*)&lo[row * 72 + ch + 16];
    uint4 x3 = *(const uint4*)&lo[row * 72 + ch + 24];
    unsigned short* dst = &Ob[(size_t)(b * SEQ + wq0 + row) * (NHEADS * HDIM) + h * HDIM + ch];
    *(uint4*)(dst + 0)  = x0;
    *(uint4*)(dst + 8)  = x1;
    *(uint4*)(dst + 16) = x2;
    *(uint4*)(dst + 24) = x3;
  }
}

// =====================================================================
// launcher
// =====================================================================
extern "C" void kernel_launch(void* const* d_in, const int* in_sizes, int n_in,
                              void* d_out, int out_size, void* d_ws, size_t ws_size,
                              hipStream_t stream) {
  const float* X  = (const float*)d_in[0];
  const float* Wq = (const float*)d_in[1];
  const float* Wk = (const float*)d_in[2];
  const float* Wv = (const float*)d_in[3];
  const float* Wo = (const float*)d_in[4];
  float* out = (float*)d_out;

  char* ws = (char*)d_ws;
  size_t off = 0;
  auto carve = [&](size_t bytes) -> void* {
    void* p = ws + off;
    off += (bytes + 255) & ~(size_t)255;
    return p;
  };
  float* rope_cos = (float*)carve((size_t)SEQ * 32 * 4);
  float* rope_sin = (float*)carve((size_t)SEQ * 32 * 4);
  unsigned short* Xb     = (unsigned short*)carve((size_t)NTOK * HIDDEN * 2);   // reused as Ob
  unsigned short* Wqkv_t = (unsigned short*)carve((size_t)QKVN * HIDDEN * 2);
  unsigned short* Wot    = (unsigned short*)carve((size_t)HIDDEN * HIDDEN * 2);
  unsigned short* QKVb   = (unsigned short*)carve((size_t)NTOK * QKVN * 2);
  unsigned short* Vt     = (unsigned short*)carve((size_t)BATCH * NKV * HDIM * SEQ * 2);
  unsigned short* Ob     = Xb;   // Xb dead after QKV GEMM

  rope_table_kernel<<<dim3(256), dim3(256), 0, stream>>>(rope_cos, rope_sin);
  convert_x_kernel<<<dim3((NTOK * HIDDEN) / (256 * 8)), dim3(256), 0, stream>>>(X, Xb);

  transpose_w_kernel<<<dim3(2048 / 64, HIDDEN / 64), dim3(256), 0, stream>>>(Wq, Wqkv_t, 2048, 0);
  transpose_w_kernel<<<dim3(512 / 64,  HIDDEN / 64), dim3(256), 0, stream>>>(Wk, Wqkv_t, 512, 2048);
  transpose_w_kernel<<<dim3(512 / 64,  HIDDEN / 64), dim3(256), 0, stream>>>(Wv, Wqkv_t, 512, 2560);
  transpose_w_kernel<<<dim3(2048 / 64, HIDDEN / 64), dim3(256), 0, stream>>>(Wo, Wot, 2048, 0);

  gemm128_kernel<true><<<dim3(QKVN / 128, NTOK / 128), dim3(256), 0, stream>>>(
      Xb, Wqkv_t, QKVb, NTOK, QKVN, HIDDEN);

  rope_apply_kernel<<<dim3((NTOK * 40) / 4), dim3(256), 0, stream>>>(QKVb, rope_cos, rope_sin);
  v_pack_kernel<<<dim3((NTOK * NKV * HDIM) / 256), dim3(256), 0, stream>>>(QKVb, Vt);

  flash_kernel<<<dim3(SEQ / 256, NHEADS, BATCH), dim3(512), 0, stream>>>(QKVb, Vt, Ob);

  gemm128_kernel<false><<<dim3(HIDDEN / 128, NTOK / 128), dim3(256), 0, stream>>>(
      Ob, Wot, out, NTOK, HIDDEN, HIDDEN);
}

// Round 5
// 336.204 us; speedup vs baseline: 3.0969x; 1.1096x over previous
//
#include <hip/hip_runtime.h>
#include <cstdint>
#include <cstddef>

// ---------- types ----------
typedef __attribute__((ext_vector_type(8))) short short8;   // 8 bf16 MFMA A/B frag
typedef __attribute__((ext_vector_type(4))) float f32x4;    // 16x16 C/D frag
typedef __attribute__((ext_vector_type(16))) float f32x16;  // 32x32 C/D frag

#define MFMA16(a, b, c) __builtin_amdgcn_mfma_f32_16x16x32_bf16((a), (b), (c), 0, 0, 0)
#define MFMA32(a, b, c) __builtin_amdgcn_mfma_f32_32x32x16_bf16((a), (b), (c), 0, 0, 0)

union F2U { float f; unsigned int u; };
union U4S8 { uint4 u4; unsigned short s[8]; short8 v; };

__device__ __forceinline__ unsigned short f2bf(float f) {
  F2U x; x.f = f;
  unsigned int r = x.u + 0x7fffu + ((x.u >> 16) & 1u);  // RNE
  return (unsigned short)(r >> 16);
}
__device__ __forceinline__ float bf2f(unsigned short s) {
  F2U x; x.u = ((unsigned int)s) << 16;
  return x.f;
}

// ---------- problem constants ----------
#define HIDDEN 2048
#define NHEADS 32
#define NKV 8
#define HDIM 64
#define SEQ 2048
#define BATCH 2
#define NTOK (BATCH * SEQ)   // 4096
#define QKVN 3072            // fused QKV output width (2048 Q | 512 K | 512 V)

// =====================================================================
// RoPE table: cos/sin [SEQ][32] fp32
// =====================================================================
__global__ __launch_bounds__(256) void rope_table_kernel(float* __restrict__ ct, float* __restrict__ st) {
  int idx = blockIdx.x * 256 + threadIdx.x;     // 0 .. 65535
  int s = idx >> 5;
  int i = idx & 31;
  float invf = expf(-(float)i * (9.210340371976184f / 32.0f));  // 10000^(-i/32)
  float f = (float)s * invf;
  ct[idx] = cosf(f);
  st[idx] = sinf(f);
}

// =====================================================================
// X fp32 -> bf16 (elementwise, vectorized)
// =====================================================================
__global__ __launch_bounds__(256) void convert_x_kernel(const float* __restrict__ X,
                                                        unsigned short* __restrict__ Xb) {
  size_t i = ((size_t)blockIdx.x * 256 + threadIdx.x) * 8;
  float4 a0 = *(const float4*)(X + i);
  float4 a1 = *(const float4*)(X + i + 4);
  U4S8 p;
  p.s[0] = f2bf(a0.x); p.s[1] = f2bf(a0.y); p.s[2] = f2bf(a0.z); p.s[3] = f2bf(a0.w);
  p.s[4] = f2bf(a1.x); p.s[5] = f2bf(a1.y); p.s[6] = f2bf(a1.z); p.s[7] = f2bf(a1.w);
  *(short8*)(Xb + i) = p.v;
}

// =====================================================================
// Weight transpose+convert: W [K=2048][N] fp32 -> Wt[row_off + n][k] bf16
// =====================================================================
__global__ __launch_bounds__(256) void transpose_w_kernel(const float* __restrict__ W,
                                                          unsigned short* __restrict__ Wt,
                                                          int N, int row_off) {
  __shared__ unsigned short lt[64][72];  // [n][k], padded
  const int t = threadIdx.x;
  const int k0 = blockIdx.y * 64, n0 = blockIdx.x * 64;
  #pragma unroll
  for (int p = 0; p < 4; ++p) {
    int kr = p * 16 + (t >> 4);
    int nc = (t & 15) * 4;
    float4 v = *(const float4*)&W[(size_t)(k0 + kr) * N + n0 + nc];
    lt[nc + 0][kr] = f2bf(v.x);
    lt[nc + 1][kr] = f2bf(v.y);
    lt[nc + 2][kr] = f2bf(v.z);
    lt[nc + 3][kr] = f2bf(v.w);
  }
  __syncthreads();
  #pragma unroll
  for (int p = 0; p < 2; ++p) {
    int nr = p * 32 + (t >> 3);
    int kc = (t & 7) * 8;
    *(short8*)&Wt[(size_t)(row_off + n0 + nr) * HIDDEN + k0 + kc] = *(const short8*)&lt[nr][kc];
  }
}

// =====================================================================
// GEMM (m97-class): C[M,N] = A[M,K] @ Bt[N,K]^T, all bf16 operands.
// 128x128 tile, BK=64, 4 waves; global_load_lds w16 + XOR chunk swizzle.
// =====================================================================
template<bool OUT_BF16>
__global__ __launch_bounds__(256) void gemm128_kernel(const unsigned short* __restrict__ Ab,
                                                      const unsigned short* __restrict__ Bt,
                                                      void* __restrict__ Cp,
                                                      int M, int N, int K) {
  __shared__ __align__(16) unsigned short lds_a[128][64];
  __shared__ __align__(16) unsigned short lds_b[128][64];

  const int t = threadIdx.x, lane = t & 63, w = t >> 6;
  const int lr = lane & 15, lh = lane >> 4;
  const int m0 = blockIdx.y * 128, n0 = blockIdx.x * 128;
  const int wr = (w >> 1) * 64, wc = (w & 1) * 64;

  f32x4 acc[4][4] = {};

  for (int k0 = 0; k0 < K; k0 += 64) {
    __syncthreads();
    #pragma unroll
    for (int c = 0; c < 4; ++c) {
      int row = w * 32 + c * 8 + (lane >> 3);
      int cks = (lane & 7) ^ (row & 7);
      __builtin_amdgcn_global_load_lds(
          (const __attribute__((address_space(1))) unsigned int*)(Ab + (size_t)(m0 + row) * K + k0 + cks * 8),
          (__attribute__((address_space(3))) unsigned int*)&lds_a[w * 32 + c * 8][0], 16, 0, 0);
      __builtin_amdgcn_global_load_lds(
          (const __attribute__((address_space(1))) unsigned int*)(Bt + (size_t)(n0 + row) * K + k0 + cks * 8),
          (__attribute__((address_space(3))) unsigned int*)&lds_b[w * 32 + c * 8][0], 16, 0, 0);
    }
    __syncthreads();

    #pragma unroll
    for (int kk = 0; kk < 2; ++kk) {
      short8 af[4], bf[4];
      #pragma unroll
      for (int i = 0; i < 4; ++i) {
        int row = wr + i * 16 + lr;
        af[i] = *(const short8*)((const char*)&lds_a[0][0] + row * 128 + (((kk * 4 + lh) ^ (row & 7)) * 16));
      }
      #pragma unroll
      for (int j = 0; j < 4; ++j) {
        int row = wc + j * 16 + lr;
        bf[j] = *(const short8*)((const char*)&lds_b[0][0] + row * 128 + (((kk * 4 + lh) ^ (row & 7)) * 16));
      }
      #pragma unroll
      for (int i = 0; i < 4; ++i)
        #pragma unroll
        for (int j = 0; j < 4; ++j)
          acc[i][j] = MFMA16(af[i], bf[j], acc[i][j]);
    }
  }

  #pragma unroll
  for (int i = 0; i < 4; ++i)
    #pragma unroll
    for (int j = 0; j < 4; ++j)
      #pragma unroll
      for (int r = 0; r < 4; ++r) {
        int row = m0 + wr + i * 16 + lh * 4 + r;
        int col = n0 + wc + j * 16 + lr;
        if constexpr (OUT_BF16)
          ((unsigned short*)Cp)[(size_t)row * N + col] = f2bf(acc[i][j][r]);
        else
          ((float*)Cp)[(size_t)row * N + col] = acc[i][j][r];
      }
}

// =====================================================================
// RoPE apply IN-PLACE on QKVb [4096][3072]; Q pre-scaled by 0.125.
// =====================================================================
__global__ __launch_bounds__(256) void rope_apply_kernel(unsigned short* __restrict__ QKV,
                                                         const float* __restrict__ ct,
                                                         const float* __restrict__ st) {
  int uid = blockIdx.x * 4 + (threadIdx.x >> 6);
  int d = threadIdx.x & 63;
  int m = uid / 40;
  int hh = uid - m * 40;
  int s = m & 2047;

  unsigned short* p = QKV + (size_t)m * QKVN + (hh < 32 ? hh * 64 : 2048 + (hh - 32) * 64);
  float v = bf2f(p[d]);
  float pr = __shfl_xor(v, 32, 64);
  int fi = d & 31;
  float c = ct[s * 32 + fi];
  float sn = st[s * 32 + fi];
  float sgn = (d < 32) ? -1.0f : 1.0f;
  float o = v * c + sgn * pr * sn;
  if (hh < 32) o *= 0.125f;
  p[d] = f2bf(o);
}

// =====================================================================
// V pack/transpose: QKVb cols 2560.. -> Vt [B][KV][64][S] bf16
// =====================================================================
__global__ __launch_bounds__(256) void v_pack_kernel(const unsigned short* __restrict__ QKV,
                                                     unsigned short* __restrict__ Vt) {
  int idx = blockIdx.x * 256 + threadIdx.x;
  int m = idx >> 9;
  int c = idx & 511;
  int b = m >> 11, s = m & 2047;
  int kv = c >> 6, d = c & 63;
  Vt[(((size_t)(b * NKV + kv)) * HDIM + d) * SEQ + s] = QKV[(size_t)m * QKVN + 2560 + c];
}

// =====================================================================
// Flash attention: 8 waves x 32 q-rows, KVBLK=64 cooperative dbuf LDS
// staging (global_load_lds w16, both-sides XOR swizzle), swapped QK^T
// 32x32 MFMA. The staged 64-key tile is processed as TWO sequential
// 32-key halves reusing one score/pack register set (spill fix vs R4).
// =====================================================================
#define KVBLK 64

__global__ __launch_bounds__(512, 4) void flash_kernel(const unsigned short* __restrict__ QKV,
                                                       const unsigned short* __restrict__ Vt,
                                                       unsigned short* __restrict__ Ob) {
  const int qb = (int)gridDim.x - 1 - (int)blockIdx.x;  // heavy blocks first
  const int h = blockIdx.y;
  const int b = blockIdx.z;
  const int kv = h >> 2;
  const int t = threadIdx.x;
  const int lane = t & 63;
  const int w = t >> 6;          // 0..7
  const int q = lane & 31;
  const int hi = lane >> 5;

  // [0,16384): K dbuf [2][64][64] bf16 ; [16384,32768): V dbuf [2][64][64]
  // epilogue: whole region reused as per-wave transpose buffers [8][32*72]
  __shared__ __align__(16) char smem[36864];
  unsigned short* Klds = (unsigned short*)smem;
  unsigned short* Vlds = (unsigned short*)(smem + 16384);

  const unsigned short* Kg = QKV + (size_t)b * SEQ * QKVN + 2048 + kv * 64;
  const unsigned short* Vg = Vt + ((size_t)(b * NKV + kv)) * HDIM * SEQ;

  const int wq0 = qb * 256 + w * 32;

  // Q B-frags (pre-scaled by 0.125): qf[f] = Q[wq0+q][f*16+hi*8 ..]
  const unsigned short* Qh = QKV + (size_t)b * SEQ * QKVN + h * 64;
  short8 qf[4];
  #pragma unroll
  for (int f = 0; f < 4; ++f)
    qf[f] = *(const short8*)&Qh[(size_t)(wq0 + q) * QKVN + f * 16 + hi * 8];

  // staging: wave w covers rows [w*8, w*8+8); lane l -> row w*8+(l>>3),
  // chunk slot l&7; source chunk inverse-swizzled so read-side XOR works.
  const int srow = w * 8 + (lane >> 3);
  const int scks = (lane & 7) ^ (srow & 7);
  const unsigned short* Ksrc = Kg + (size_t)srow * QKVN + scks * 8;   // + (kt0)*QKVN
  const unsigned short* Vsrc = Vg + (size_t)srow * SEQ + scks * 8;    // + kt0

  #define STAGE_KV(buf, kt0)                                                              \
    do {                                                                                  \
      __builtin_amdgcn_global_load_lds(                                                   \
          (const __attribute__((address_space(1))) unsigned int*)(Ksrc + (size_t)(kt0) * QKVN), \
          (__attribute__((address_space(3))) unsigned int*)(Klds + (buf) * 4096 + w * 512), 16, 0, 0); \
      __builtin_amdgcn_global_load_lds(                                                   \
          (const __attribute__((address_space(1))) unsigned int*)(Vsrc + (kt0)),          \
          (__attribute__((address_space(3))) unsigned int*)(Vlds + (buf) * 4096 + w * 512), 16, 0, 0); \
    } while (0)

  f32x16 o0 = {}, o1 = {};
  float m_run = -1e30f, l_run = 0.f;

  const int nt_blk = qb * 4 + 4;            // tiles staged by the block
  const int nt_w   = qb * 4 + (w >> 1) + 1; // tiles this wave computes

  STAGE_KV(0, 0);
  __syncthreads();
  int cur = 0;

  for (int tt = 0; tt < nt_blk; ++tt) {
    if (tt + 1 < nt_blk) STAGE_KV(cur ^ 1, (tt + 1) * KVBLK);

    if (tt < nt_w) {
      const int kt0 = tt * KVBLK;
      const unsigned short* Kt = Klds + cur * 4096;
      const unsigned short* Vl = Vlds + cur * 4096;

      #pragma unroll
      for (int hk = 0; hk < 2; ++hk) {
        const int kbase = kt0 + hk * 32;
        if (kbase <= wq0 + 31) {          // wave-uniform: not fully masked
          // ---- S^T = K Q^T (one 32-key half) ----
          f32x16 s = {};
          __builtin_amdgcn_s_setprio(1);
          #pragma unroll
          for (int f = 0; f < 4; ++f) {
            short8 kf = *(const short8*)(Kt + (hk * 32 + q) * 64 + (((f * 2 + hi) ^ (q & 7)) * 8));
            s = MFMA32(kf, qf[f], s);
          }
          __builtin_amdgcn_s_setprio(0);

          // ---- causal mask (diagonal half only) ----
          if (kbase + 31 > wq0) {
            #pragma unroll
            for (int r = 0; r < 16; ++r) {
              int kl = (r & 3) + 8 * (r >> 2) + 4 * hi;
              if (kbase + kl > wq0 + q) s[r] = -1e30f;
            }
          }

          // ---- row max ----
          float mt = -1e30f;
          #pragma unroll
          for (int r = 0; r < 16; ++r) mt = fmaxf(mt, s[r]);
          mt = fmaxf(mt, __shfl_xor(mt, 32, 64));

          // ---- online softmax ----
          float mn = fmaxf(m_run, mt);
          float alpha = __expf(m_run - mn);
          m_run = mn;
          float ls = 0.f;
          #pragma unroll
          for (int r = 0; r < 16; ++r) {
            float p = __expf(s[r] - mn);
            s[r] = p;
            ls += p;
          }
          ls += __shfl_xor(ls, 32, 64);
          l_run = l_run * alpha + ls;
          #pragma unroll
          for (int r = 0; r < 16; ++r) { o0[r] *= alpha; o1[r] *= alpha; }

          // ---- pack P -> bf16 words, exchange halves ----
          unsigned int own[8], rcv[8];
          #pragma unroll
          for (int g = 0; g < 8; ++g)
            own[g] = (unsigned int)f2bf(s[2 * g]) | ((unsigned int)f2bf(s[2 * g + 1]) << 16);
          #pragma unroll
          for (int g = 0; g < 8; ++g)
            rcv[g] = (unsigned int)__shfl_xor((int)own[g], 32, 64);

          // ---- P^T frags + PV (2 slices of 16 keys) ----
          __builtin_amdgcn_s_setprio(1);
          #pragma unroll
          for (int ks = 0; ks < 2; ++ks) {
            U4S8 pfv;
            int w0 = 4 * ks + 2 * hi;
            pfv.u4.x = hi ? rcv[w0]     : own[w0];
            pfv.u4.y = hi ? rcv[w0 + 1] : own[w0 + 1];
            pfv.u4.z = hi ? own[w0]     : rcv[w0];
            pfv.u4.w = hi ? own[w0 + 1] : rcv[w0 + 1];
            int co = ((hk * 4 + ks * 2 + hi) ^ (q & 7)) * 8;
            short8 vf0 = *(const short8*)(Vl + q * 64 + co);
            short8 vf1 = *(const short8*)(Vl + (32 + q) * 64 + co);
            o0 = MFMA32(vf0, pfv.v, o0);
            o1 = MFMA32(vf1, pfv.v, o1);
          }
          __builtin_amdgcn_s_setprio(0);
        }
      }
    }

    __syncthreads();
    cur ^= 1;
  }

  // ---- epilogue: normalize, per-wave LDS transpose (aliases K/V), store ----
  unsigned short* lo = (unsigned short*)smem + (size_t)w * 32 * 72;
  float inv = 1.0f / l_run;
  #pragma unroll
  for (int gg = 0; gg < 8; ++gg) {
    int r = 2 * gg;
    int dl = (r & 3) + 8 * (r >> 2) + 4 * hi;
    unsigned int w0 = (unsigned int)f2bf(o0[r] * inv) | ((unsigned int)f2bf(o0[r + 1] * inv) << 16);
    unsigned int w1 = (unsigned int)f2bf(o1[r] * inv) | ((unsigned int)f2bf(o1[r + 1] * inv) << 16);
    *(unsigned int*)&lo[q * 72 + dl] = w0;
    *(unsigned int*)&lo[q * 72 + 32 + dl] = w1;
  }
  {
    int row = lane >> 1;
    int ch = (lane & 1) * 32;
    uint4 x0 = *(const uint4*)&lo[row * 72 + ch + 0];
    uint4 x1 = *(const uint4*)&lo[row * 72 + ch + 8];
    uint4 x2 = *(const uint4*)&lo[row * 72 + ch + 16];
    uint4 x3 = *(const uint4*)&lo[row * 72 + ch + 24];
    unsigned short* dst = &Ob[(size_t)(b * SEQ + wq0 + row) * (NHEADS * HDIM) + h * HDIM + ch];
    *(uint4*)(dst + 0)  = x0;
    *(uint4*)(dst + 8)  = x1;
    *(uint4*)(dst + 16) = x2;
    *(uint4*)(dst + 24) = x3;
  }
}

// =====================================================================
// launcher
// =====================================================================
extern "C" void kernel_launch(void* const* d_in, const int* in_sizes, int n_in,
                              void* d_out, int out_size, void* d_ws, size_t ws_size,
                              hipStream_t stream) {
  const float* X  = (const float*)d_in[0];
  const float* Wq = (const float*)d_in[1];
  const float* Wk = (const float*)d_in[2];
  const float* Wv = (const float*)d_in[3];
  const float* Wo = (const float*)d_in[4];
  float* out = (float*)d_out;

  char* ws = (char*)d_ws;
  size_t off = 0;
  auto carve = [&](size_t bytes) -> void* {
    void* p = ws + off;
    off += (bytes + 255) & ~(size_t)255;
    return p;
  };
  float* rope_cos = (float*)carve((size_t)SEQ * 32 * 4);
  float* rope_sin = (float*)carve((size_t)SEQ * 32 * 4);
  unsigned short* Xb     = (unsigned short*)carve((size_t)NTOK * HIDDEN * 2);   // reused as Ob
  unsigned short* Wqkv_t = (unsigned short*)carve((size_t)QKVN * HIDDEN * 2);
  unsigned short* Wot    = (unsigned short*)carve((size_t)HIDDEN * HIDDEN * 2);
  unsigned short* QKVb   = (unsigned short*)carve((size_t)NTOK * QKVN * 2);
  unsigned short* Vt     = (unsigned short*)carve((size_t)BATCH * NKV * HDIM * SEQ * 2);
  unsigned short* Ob     = Xb;   // Xb dead after QKV GEMM

  rope_table_kernel<<<dim3(256), dim3(256), 0, stream>>>(rope_cos, rope_sin);
  convert_x_kernel<<<dim3((NTOK * HIDDEN) / (256 * 8)), dim3(256), 0, stream>>>(X, Xb);

  transpose_w_kernel<<<dim3(2048 / 64, HIDDEN / 64), dim3(256), 0, stream>>>(Wq, Wqkv_t, 2048, 0);
  transpose_w_kernel<<<dim3(512 / 64,  HIDDEN / 64), dim3(256), 0, stream>>>(Wk, Wqkv_t, 512, 2048);
  transpose_w_kernel<<<dim3(512 / 64,  HIDDEN / 64), dim3(256), 0, stream>>>(Wv, Wqkv_t, 512, 2560);
  transpose_w_kernel<<<dim3(2048 / 64, HIDDEN / 64), dim3(256), 0, stream>>>(Wo, Wot, 2048, 0);

  gemm128_kernel<true><<<dim3(QKVN / 128, NTOK / 128), dim3(256), 0, stream>>>(
      Xb, Wqkv_t, QKVb, NTOK, QKVN, HIDDEN);

  rope_apply_kernel<<<dim3((NTOK * 40) / 4), dim3(256), 0, stream>>>(QKVb, rope_cos, rope_sin);
  v_pack_kernel<<<dim3((NTOK * NKV * HDIM) / 256), dim3(256), 0, stream>>>(QKVb, Vt);

  flash_kernel<<<dim3(SEQ / 256, NHEADS, BATCH), dim3(512), 0, stream>>>(QKVb, Vt, Ob);

  gemm128_kernel<false><<<dim3(HIDDEN / 128, NTOK / 128), dim3(256), 0, stream>>>(
      Ob, Wot, out, NTOK, HIDDEN, HIDDEN);
}